// Round 1
// baseline (238.692 us; speedup 1.0000x reference)
//
#include <hip/hip_runtime.h>

typedef unsigned short u16;
typedef __attribute__((ext_vector_type(8))) short bh8;     // 8 bf16 MFMA A/B frag
typedef __attribute__((ext_vector_type(4))) float f4;      // MFMA C/D frag / float4
typedef __attribute__((ext_vector_type(4))) unsigned short us4;

#define T_SEQ 2048
#define NHEADS 16
#define DHEAD 64
#define WIN 256

#define MF(a, b, c) __builtin_amdgcn_mfma_f32_16x16x32_bf16((a), (b), (c), 0, 0, 0)
#define BARX() asm volatile("s_barrier" ::: "memory")
#define VMCNT(n) asm volatile("s_waitcnt vmcnt(" #n ")" ::: "memory")

__device__ __forceinline__ float bf2f(u16 u) {
  union { unsigned int i; float f; } v; v.i = ((unsigned int)u) << 16; return v.f;
}
__device__ __forceinline__ u16 f2bf(float f) {
  unsigned int u = __float_as_uint(f);
  u = u + 0x7fffu + ((u >> 16) & 1u);   // RNE
  return (u16)(u >> 16);
}
__device__ __forceinline__ void async16(const void* g, void* l) {
  void* gv = const_cast<void*>(g);
  __builtin_amdgcn_global_load_lds(
      (__attribute__((address_space(1))) void*)gv,
      (__attribute__((address_space(3))) void*)l, 16, 0, 0);
}

// Inline dtype probe: 1 if x[0..255] plausible as fp32. Wave-uniform (ballot),
// deterministic across all blocks/kernels -> no separate detect kernel needed.
__device__ __forceinline__ int is_f32_probe(const void* x) {
  const float* xf = (const float*)x;
  const int lane = threadIdx.x & 63;
  int bad = 0;
  #pragma unroll
  for (int u = 0; u < 4; ++u) {
    const float v = xf[lane * 4 + u];
    const float a = fabsf(v);
    bad |= (!(a < 64.f)) || (!(v == 0.f || a > 1e-30f));
  }
  return __any(bad) ? 0 : 1;
}

// ---------------- fused prep: xconv + transpose(w_qkv) + transpose(w_out) ------------
__global__ __launch_bounds__(256) void prep(
    const void* __restrict__ x, const void* __restrict__ w_qkv,
    const void* __restrict__ w_out, u16* __restrict__ xbf,
    u16* __restrict__ wqkvT, u16* __restrict__ woutT, int have_x)
{
  const int bid = blockIdx.x;
  const int tid = threadIdx.x;
  const int isf = is_f32_probe(x);

  if (bid < 4096) {                       // ---- xconv ----
    if (!have_x) return;
    const size_t e = ((size_t)bid * 256 + tid) * 8;
    if (isf) {
      const float* f = (const float*)x;
      us4 o0, o1;
      #pragma unroll
      for (int u = 0; u < 4; ++u) { o0[u] = f2bf(f[e + u]); o1[u] = f2bf(f[e + 4 + u]); }
      *(us4*)&xbf[e] = o0; *(us4*)&xbf[e + 4] = o1;
    } else {
      *(us4*)&xbf[e]     = *(const us4*)&((const u16*)x)[e];
      *(us4*)&xbf[e + 4] = *(const us4*)&((const u16*)x)[e + 4];
    }
  } else {                                // ---- transposes ----
    __shared__ alignas(16) u16 tile[32][33];
    const void* in; u16* out; int C, bx, by;
    if (bid < 4096 + 3072) { const int t = bid - 4096; in = w_qkv; out = wqkvT; C = 3072; bx = t % 96; by = t / 96; }
    else                   { const int t = bid - 7168; in = w_out; out = woutT; C = 1024; bx = t % 32; by = t / 32; }
    const int R = 1024;
    const int tx = tid & 31, ty = tid >> 5;
    const int xg = bx * 32 + tx;
    const int y0 = by * 32;
    #pragma unroll
    for (int i = ty; i < 32; i += 8) {
      u16 v;
      if (isf) v = f2bf(((const float*)in)[(size_t)(y0 + i) * C + xg]);
      else     v = ((const u16*)in)[(size_t)(y0 + i) * C + xg];
      tile[i][tx] = v;
    }
    __syncthreads();
    const int ox  = y0 + tx;
    const int oy0 = bx * 32;
    #pragma unroll
    for (int i = ty; i < 32; i += 8)
      out[(size_t)(oy0 + i) * R + ox] = tile[tx][i];
  }
}

// ---------------- legacy bf16 GEMM (kept only for the fp32-A fallback path) ---------
template<bool ADYN, bool CDYN>
__global__ __launch_bounds__(256, 4) void gemm_bt(
    const void* __restrict__ A, const u16* __restrict__ Bt,
    void* __restrict__ C, int N, int K, int lda, int ldc,
    const void* __restrict__ xprobe)
{
  __shared__ alignas(16) u16 As[128 * 64];
  __shared__ alignas(16) u16 Bs[128 * 64];

  const int isf  = (ADYN || CDYN) ? is_f32_probe(xprobe) : 0;
  const int tid  = threadIdx.x;
  const int lane = tid & 63;
  const int w    = tid >> 6;
  const int wm   = (w >> 1) * 64;
  const int wn   = (w & 1) * 64;
  const int quad = lane >> 4;
  const int l16  = lane & 15;
  const int row0 = blockIdx.y * 128;
  const int col0 = blockIdx.x * 128;

  f4 acc[4][4] = {};

  size_t aoff[4]; const u16* bsrc[4]; int lofs[4];
  #pragma unroll
  for (int s = 0; s < 4; ++s) {
    const int r  = s * 32 + (tid >> 3);
    const int gc = (tid & 7) ^ (r & 7);
    aoff[s] = (size_t)(row0 + r) * lda + gc * 8;
    bsrc[s] = Bt + (size_t)(col0 + r) * K + gc * 8;
    lofs[s] = s * 4096 + tid * 16;
  }

  const bool af32 = ADYN && isf;

  for (int k0 = 0; k0 < K; k0 += 64) {
    if (af32) {
      const float* Af = (const float*)A;
      bh8 a[4];
      #pragma unroll
      for (int s = 0; s < 4; ++s) {
        f4 u0 = *(const f4*)(Af + aoff[s] + k0);
        f4 u1 = *(const f4*)(Af + aoff[s] + k0 + 4);
        #pragma unroll
        for (int u = 0; u < 4; ++u) { a[s][u] = (short)f2bf(u0[u]); a[s][u + 4] = (short)f2bf(u1[u]); }
      }
      __syncthreads();
      #pragma unroll
      for (int s = 0; s < 4; ++s) {
        *(bh8*)((char*)As + lofs[s]) = a[s];
        async16(bsrc[s] + k0, (char*)Bs + lofs[s]);
      }
    } else {
      const u16* A16 = (const u16*)A;
      __syncthreads();
      #pragma unroll
      for (int s = 0; s < 4; ++s) {
        async16(A16 + aoff[s] + k0, (char*)As + lofs[s]);
        async16(bsrc[s] + k0,       (char*)Bs + lofs[s]);
      }
    }
    __builtin_amdgcn_s_waitcnt(0);
    __syncthreads();

    #pragma unroll
    for (int ks = 0; ks < 2; ++ks) {
      bh8 af[4], bf[4];
      #pragma unroll
      for (int i = 0; i < 4; ++i) {
        const int row = wm + i * 16 + l16;
        const int lc  = (ks * 4 + quad) ^ (row & 7);
        af[i] = *(const bh8*)(As + row * 64 + lc * 8);
      }
      #pragma unroll
      for (int j = 0; j < 4; ++j) {
        const int row = wn + j * 16 + l16;
        const int lc  = (ks * 4 + quad) ^ (row & 7);
        bf[j] = *(const bh8*)(Bs + row * 64 + lc * 8);
      }
      #pragma unroll
      for (int i = 0; i < 4; ++i)
        #pragma unroll
        for (int j = 0; j < 4; ++j)
          acc[i][j] = MF(af[i], bf[j], acc[i][j]);
    }
  }

  const bool cf32 = CDYN && isf;
  #pragma unroll
  for (int i = 0; i < 4; ++i) {
    #pragma unroll
    for (int j = 0; j < 4; ++j) {
      const int rb = row0 + wm + i * 16 + quad * 4;
      const int cc = col0 + wn + j * 16 + l16;
      #pragma unroll
      for (int r = 0; r < 4; ++r) {
        if (cf32) ((float*)C)[(size_t)(rb + r) * ldc + cc] = acc[i][j][r];
        else      ((u16*)C)[(size_t)(rb + r) * ldc + cc]   = f2bf(acc[i][j][r]);
      }
    }
  }
}

// ---------------- 8-wave 256x128 phase-scheduled GEMM (T2+T3+T4+T5) ----------------
// C[M,N] = A[M,K(lda)] * Bt[N,K]^T, bf16 in, bf16/f32 out. BK=64.
// Triple-buffered LDS (144 KB, 1 block/CU), 4 phases per K-tile:
//   {ds_read frag subtile | issue global_load_lds for tile kt+2 | barrier |
//    setprio(1) | 8 MFMA | setprio(0) | barrier}
// Counted vmcnt(6) once per K-tile: tile kt+2's 6 loads (A x4, B x2) stay in
// flight across the tile boundary (FIFO vmcnt => tile kt+1 fully landed).
// LDS slot (row, c) holds global chunk c^(row&7) -> conflict-free b128 reads
// (same swizzle as legacy kernel; measured 0 bank conflicts).
template<bool CDYN>
__global__ __launch_bounds__(512, 2) void gemm8(
    const u16* __restrict__ A, const u16* __restrict__ Bt, void* __restrict__ C,
    int K, int lda, int ldc, const void* __restrict__ xprobe)
{
  __shared__ alignas(16) u16 As[3 * 256 * 64];   // 96 KB
  __shared__ alignas(16) u16 Bs[3 * 128 * 64];   // 48 KB

  const int isf  = CDYN ? is_f32_probe(xprobe) : 0;
  const int tid  = threadIdx.x;
  const int lane = tid & 63;
  const int w    = tid >> 6;
  const int wm   = (w >> 1) * 64;                // 4 M-groups of 64
  const int wn   = (w & 1) * 64;                 // 2 N-groups of 64
  const int quad = lane >> 4;
  const int l16  = lane & 15;
  const int row0 = blockIdx.y * 256;
  const int col0 = blockIdx.x * 128;

  f4 acc[4][4] = {};

  // staging: per K-tile, A = 4 loads (256x64), B = 2 loads (128x64).
  // thread t covers row (s*64 + t/8), global chunk (t&7)^(row&7) -> LDS (row, t&7)
  const int rs = tid >> 3;
  const int cs = tid & 7;
  const u16* apt[4]; const u16* bpt[2]; int aofs[4], bofs[2];
  #pragma unroll
  for (int s = 0; s < 4; ++s) {
    const int r = s * 64 + rs;
    apt[s]  = A + (size_t)(row0 + r) * lda + (cs ^ (r & 7)) * 8;
    aofs[s] = s * 8192 + tid * 16;               // bytes within one A buffer
  }
  #pragma unroll
  for (int s = 0; s < 2; ++s) {
    const int r = s * 64 + rs;
    bpt[s]  = Bt + (size_t)(col0 + r) * K + (cs ^ (r & 7)) * 8;
    bofs[s] = s * 8192 + tid * 16;               // bytes within one B buffer
  }

  const int NK = K >> 6;

  // frag-read offsets (row&7 == l16&7 since wm,i*16 are multiples of 16)
  const int sw = l16 & 7;
  const int c0 = ((quad    ) ^ sw) * 8;          // k-chunk for ks=0
  const int c1 = ((quad + 4) ^ sw) * 8;          // k-chunk for ks=1
  const int ra0 = (wm      + l16) * 64, ra1 = (wm + 16 + l16) * 64,
            ra2 = (wm + 32 + l16) * 64, ra3 = (wm + 48 + l16) * 64;
  const int rb0 = (wn      + l16) * 64, rb1 = (wn + 16 + l16) * 64,
            rb2 = (wn + 32 + l16) * 64, rb3 = (wn + 48 + l16) * 64;

  // prologue: stage tiles 0,1 into bufs 0,1 (issue order per tile: A0..A3,B0,B1)
  #pragma unroll
  for (int s = 0; s < 4; ++s) async16(apt[s], (char*)As + aofs[s]);
  #pragma unroll
  for (int s = 0; s < 2; ++s) async16(bpt[s], (char*)Bs + bofs[s]);
  if (NK > 1) {
    #pragma unroll
    for (int s = 0; s < 4; ++s) async16(apt[s] + 64, (char*)As + 32768 + aofs[s]);
    #pragma unroll
    for (int s = 0; s < 2; ++s) async16(bpt[s] + 64, (char*)Bs + 16384 + bofs[s]);
    VMCNT(6);                                    // tile 0 landed; tile 1 in flight
  } else {
    VMCNT(0);
  }
  BARX();

  int cb = 0, sb = 2;                            // compute buf, stage buf (kt+2)
  for (int kt = 0; kt < NK; ++kt) {
    const u16* Ab = As + cb * 16384;
    const u16* Bb = Bs + cb * 8192;
    char* Asb = (char*)As + sb * 32768;
    char* Bsb = (char*)Bs + sb * 16384;
    const bool st = (kt + 2) < NK;
    const int k2 = (kt + 2) * 64;

    // ---- phase 0: read a0,a1,b0,b1; stage A halves 0,1 of tile kt+2
    bh8 a00 = *(const bh8*)(Ab + ra0 + c0), a01 = *(const bh8*)(Ab + ra0 + c1);
    bh8 a10 = *(const bh8*)(Ab + ra1 + c0), a11 = *(const bh8*)(Ab + ra1 + c1);
    bh8 b00 = *(const bh8*)(Bb + rb0 + c0), b01 = *(const bh8*)(Bb + rb0 + c1);
    bh8 b10 = *(const bh8*)(Bb + rb1 + c0), b11 = *(const bh8*)(Bb + rb1 + c1);
    if (st) { async16(apt[0] + k2, Asb + aofs[0]);
              async16(apt[1] + k2, Asb + aofs[1]); }
    BARX();
    __builtin_amdgcn_s_setprio(1);
    acc[0][0] = MF(a01, b01, MF(a00, b00, acc[0][0]));
    acc[0][1] = MF(a01, b11, MF(a00, b10, acc[0][1]));
    acc[1][0] = MF(a11, b01, MF(a10, b00, acc[1][0]));
    acc[1][1] = MF(a11, b11, MF(a10, b10, acc[1][1]));
    __builtin_amdgcn_s_setprio(0);
    BARX();

    // ---- phase 1: read a2,a3; stage A halves 2,3
    bh8 a20 = *(const bh8*)(Ab + ra2 + c0), a21 = *(const bh8*)(Ab + ra2 + c1);
    bh8 a30 = *(const bh8*)(Ab + ra3 + c0), a31 = *(const bh8*)(Ab + ra3 + c1);
    if (st) { async16(apt[2] + k2, Asb + aofs[2]);
              async16(apt[3] + k2, Asb + aofs[3]); }
    BARX();
    __builtin_amdgcn_s_setprio(1);
    acc[2][0] = MF(a21, b01, MF(a20, b00, acc[2][0]));
    acc[2][1] = MF(a21, b11, MF(a20, b10, acc[2][1]));
    acc[3][0] = MF(a31, b01, MF(a30, b00, acc[3][0]));
    acc[3][1] = MF(a31, b11, MF(a30, b10, acc[3][1]));
    __builtin_amdgcn_s_setprio(0);
    BARX();

    // ---- phase 2: read b2,b3; stage B half 0
    bh8 b20 = *(const bh8*)(Bb + rb2 + c0), b21 = *(const bh8*)(Bb + rb2 + c1);
    bh8 b30 = *(const bh8*)(Bb + rb3 + c0), b31 = *(const bh8*)(Bb + rb3 + c1);
    if (st) async16(bpt[0] + k2, Bsb + bofs[0]);
    BARX();
    __builtin_amdgcn_s_setprio(1);
    acc[0][2] = MF(a01, b21, MF(a00, b20, acc[0][2]));
    acc[0][3] = MF(a01, b31, MF(a00, b30, acc[0][3]));
    acc[1][2] = MF(a11, b21, MF(a10, b20, acc[1][2]));
    acc[1][3] = MF(a11, b31, MF(a10, b30, acc[1][3]));
    __builtin_amdgcn_s_setprio(0);
    BARX();

    // ---- phase 3: stage B half 1; counted vmcnt at the tile boundary
    if (st) async16(bpt[1] + k2, Bsb + bofs[1]);
    BARX();
    __builtin_amdgcn_s_setprio(1);
    acc[2][2] = MF(a21, b21, MF(a20, b20, acc[2][2]));
    acc[2][3] = MF(a21, b31, MF(a20, b30, acc[2][3]));
    acc[3][2] = MF(a31, b21, MF(a30, b20, acc[3][2]));
    acc[3][3] = MF(a31, b31, MF(a30, b30, acc[3][3]));
    __builtin_amdgcn_s_setprio(0);
    if (st) VMCNT(6);                            // keep kt+2's 6 loads in flight
    else    VMCNT(0);                            // tail: drain (last 2 iters only)
    BARX();

    cb = (cb == 2) ? 0 : cb + 1;
    sb = (sb == 2) ? 0 : sb + 1;
  }

  // epilogue
  const bool cf32 = CDYN && isf;
  #pragma unroll
  for (int i = 0; i < 4; ++i) {
    #pragma unroll
    for (int j = 0; j < 4; ++j) {
      const int rb = row0 + wm + i * 16 + quad * 4;
      const int cc = col0 + wn + j * 16 + l16;
      #pragma unroll
      for (int r = 0; r < 4; ++r) {
        if (cf32) ((float*)C)[(size_t)(rb + r) * ldc + cc] = acc[i][j][r];
        else      ((u16*)C)[(size_t)(rb + r) * ldc + cc]   = f2bf(acc[i][j][r]);
      }
    }
  }
}

// ---------------- MFMA flash-style sliding-window attention ----------------
// Q frags in registers; LDS = Kt+Vt+Ps = 27.6 KB -> 5 blocks/CU.
// Output -> att matrix [B*T, ldo] at column h*64 (ldo=1024 compact, or
// ldo=3072 with att=qkv for the in-place q-channel fallback).
__global__ __launch_bounds__(256) void attn_mfma(const u16* __restrict__ qkv,
                                                 u16* __restrict__ att, int ldo)
{
  __shared__ alignas(16) u16 Kt[64 * 72];
  __shared__ alignas(16) u16 Vt[64 * 72];   // (d,k): d*72 + ((k>>3)^(d>>3))*8 + (k&7)
  __shared__ alignas(16) u16 Ps[64 * 72];   // (q,k): q*72 + ((k>>3)^((q>>3)&1))*8 + (k&7)

  const int tid  = threadIdx.x;
  const int lane = tid & 63;
  const int w    = tid >> 6;
  const int quad = lane >> 4;
  const int l16  = lane & 15;
  const int qb = blockIdx.x, h = blockIdx.y, b = blockIdx.z;
  const int qs = qb * 64;

  const u16* base = qkv + (size_t)b * T_SEQ * 3072 + h * 64;

  const size_t qrowg = (size_t)(qs + w * 16 + l16) * 3072;
  bh8 qa0 = *(const bh8*)&base[qrowg + quad * 8];
  bh8 qa1 = *(const bh8*)&base[qrowg + 32 + quad * 8];

  f4 Oc[4] = {};
  float mst[4] = {-1e30f, -1e30f, -1e30f, -1e30f};
  float lst[4] = {0.f, 0.f, 0.f, 0.f};

  const int tmin = (qb >= 4) ? 0 : (4 - qb);
  const int c8  = (tid & 7) * 8;
  const int r0s = tid >> 3;

  for (int t = tmin; t < 5; ++t) {
    const int kt0 = qs - 256 + t * 64;
    __syncthreads();

    #pragma unroll
    for (int r = r0s; r < 64; r += 32) {
      *(bh8*)&Kt[r * 72 + c8] =
          *(const bh8*)&base[(size_t)(kt0 + r) * 3072 + 1024 + c8];
      bh8 v = *(const bh8*)&base[(size_t)(kt0 + r) * 3072 + 2048 + c8];
      const int kc = r >> 3, ki = r & 7;
      #pragma unroll
      for (int u = 0; u < 8; ++u) {
        const int d = c8 + u;
        Vt[d * 72 + ((kc ^ (d >> 3)) << 3) + ki] = (u16)v[u];
      }
    }
    __syncthreads();

    f4 S[4];
    #pragma unroll
    for (int kb = 0; kb < 4; ++kb) {
      const int krow = (kb * 16 + l16) * 72;
      bh8 kf0 = *(const bh8*)&Kt[krow + quad * 8];
      bh8 kf1 = *(const bh8*)&Kt[krow + 32 + quad * 8];
      f4 s = {};
      s = __builtin_amdgcn_mfma_f32_16x16x32_bf16(qa0, kf0, s, 0, 0, 0);
      s = __builtin_amdgcn_mfma_f32_16x16x32_bf16(qa1, kf1, s, 0, 0, 0);
      S[kb] = s;
    }

    const int iq0 = qs + w * 16 + quad * 4;
    float tmax[4] = {-1e30f, -1e30f, -1e30f, -1e30f};
    #pragma unroll
    for (int kb = 0; kb < 4; ++kb) {
      const int j = kt0 + kb * 16 + l16;
      #pragma unroll
      for (int rr = 0; rr < 4; ++rr) {
        const int i = iq0 + rr;
        float s = S[kb][rr] * 0.125f;
        const bool ok = (j <= i) && (j > i - WIN);
        s = ok ? s : -1e30f;
        S[kb][rr] = s;
        tmax[rr] = fmaxf(tmax[rr], s);
      }
    }
    #pragma unroll
    for (int off = 1; off < 16; off <<= 1)
      #pragma unroll
      for (int rr = 0; rr < 4; ++rr)
        tmax[rr] = fmaxf(tmax[rr], __shfl_xor(tmax[rr], off));

    float alpha[4], rsum[4];
    #pragma unroll
    for (int rr = 0; rr < 4; ++rr) {
      const float mnew = fmaxf(mst[rr], tmax[rr]);
      alpha[rr] = __expf(mst[rr] - mnew);
      mst[rr] = mnew;
      rsum[rr] = 0.f;
    }

    const int swq = quad >> 1;
    #pragma unroll
    for (int kb = 0; kb < 4; ++kb) {
      const int kc = kb * 2 + (l16 >> 3);
      const int ki = l16 & 7;
      #pragma unroll
      for (int rr = 0; rr < 4; ++rr) {
        const float sv = S[kb][rr];
        const float p = (sv > -0.5e30f) ? __expf(sv - mst[rr]) : 0.f;
        rsum[rr] += p;
        const int q = w * 16 + quad * 4 + rr;
        Ps[q * 72 + ((kc ^ swq) << 3) + ki] = f2bf(p);
      }
    }
    #pragma unroll
    for (int off = 1; off < 16; off <<= 1)
      #pragma unroll
      for (int rr = 0; rr < 4; ++rr)
        rsum[rr] += __shfl_xor(rsum[rr], off);
    #pragma unroll
    for (int rr = 0; rr < 4; ++rr)
      lst[rr] = lst[rr] * alpha[rr] + rsum[rr];

    #pragma unroll
    for (int db = 0; db < 4; ++db)
      #pragma unroll
      for (int rr = 0; rr < 4; ++rr)
        Oc[db][rr] *= alpha[rr];

    {
      const int q = w * 16 + l16;
      const int sw = (q >> 3) & 1;
      bh8 pa0 = *(const bh8*)&Ps[q * 72 + (((0 + quad) ^ sw) << 3)];
      bh8 pa1 = *(const bh8*)&Ps[q * 72 + (((4 + quad) ^ sw) << 3)];
      #pragma unroll
      for (int db = 0; db < 4; ++db) {
        const int d = db * 16 + l16;
        const int dsw = d >> 3;
        bh8 vb0 = *(const bh8*)&Vt[d * 72 + (((0 + quad) ^ dsw) << 3)];
        bh8 vb1 = *(const bh8*)&Vt[d * 72 + (((4 + quad) ^ dsw) << 3)];
        Oc[db] = __builtin_amdgcn_mfma_f32_16x16x32_bf16(pa0, vb0, Oc[db], 0, 0, 0);
        Oc[db] = __builtin_amdgcn_mfma_f32_16x16x32_bf16(pa1, vb1, Oc[db], 0, 0, 0);
      }
    }
  }

  u16* obase = att + (size_t)b * T_SEQ * ldo + h * 64;
  #pragma unroll
  for (int rr = 0; rr < 4; ++rr) {
    const int i = qs + w * 16 + quad * 4 + rr;
    const float inv = 1.f / lst[rr];
    #pragma unroll
    for (int db = 0; db < 4; ++db)
      obase[(size_t)i * ldo + db * 16 + l16] = f2bf(Oc[db][rr] * inv);
  }
}

// ---------------- launcher ----------------
extern "C" void kernel_launch(void* const* d_in, const int* in_sizes, int n_in,
                              void* d_out, int out_size, void* d_ws, size_t ws_size,
                              hipStream_t stream) {
  const void* x     = d_in[0];   // [8192, 1024]  fp32 or bf16 (auto-detected)
  const void* w_qkv = d_in[1];   // [1024, 3072]
  const void* w_out = d_in[2];   // [1024, 1024]

  const size_t SZ_QKV = (size_t)8192 * 3072 * 2;
  const size_t SZ_XBF = (size_t)8192 * 1024 * 2;
  const size_t SZ_WQ  = (size_t)3072 * 1024 * 2;
  const size_t SZ_WO  = (size_t)1024 * 1024 * 2;
  const size_t SZ_ATT = (size_t)8192 * 1024 * 2;

  char* p = (char*)d_ws;
  u16* qkv   = (u16*)p; p += SZ_QKV;
  u16* wqkvT = (u16*)p; p += SZ_WQ;
  u16* woutT = (u16*)p; p += SZ_WO;
  u16* xbf   = (u16*)p; p += SZ_XBF;
  u16* attb  = (u16*)p;
  const size_t need_x   = SZ_QKV + SZ_WQ + SZ_WO + SZ_XBF;
  const bool have_x   = ws_size >= need_x;
  const bool have_att = ws_size >= need_x + SZ_ATT;

  prep<<<dim3(8192), 256, 0, stream>>>(x, w_qkv, w_out, xbf, wqkvT, woutT,
                                       have_x ? 1 : 0);

  if (have_x) {
    // 24x32 = 768 blocks = exactly 3 full waves at 1 block/CU
    gemm8<false><<<dim3(24, 32), 512, 0, stream>>>(
        xbf, wqkvT, qkv, 1024, 1024, 3072, x);
  } else {
    gemm_bt<true, false><<<dim3(24, 64), 256, 0, stream>>>(
        x, wqkvT, qkv, 3072, 1024, 1024, 3072, x);
  }

  // attention: compact output when ws allows, else in-place q-channel
  u16* attp  = have_att ? attb : qkv;
  const int ldo = have_att ? 1024 : 3072;
  attn_mfma<<<dim3(32, NHEADS, 4), 256, 0, stream>>>(qkv, attp, ldo);

  // 8x32 = 256 blocks = exactly 1 full wave at 1 block/CU
  gemm8<true><<<dim3(8, 32), 512, 0, stream>>>(
      attp, woutT, d_out, 1024, ldo, 1024, x);
}

// Round 3
// 226.575 us; speedup vs baseline: 1.0535x; 1.0535x over previous
//
#include <hip/hip_runtime.h>

typedef unsigned short u16;
typedef __attribute__((ext_vector_type(8))) short bh8;     // 8 bf16 MFMA A/B frag
typedef __attribute__((ext_vector_type(4))) float f4;      // MFMA C/D frag / float4
typedef __attribute__((ext_vector_type(4))) unsigned short us4;

#define T_SEQ 2048
#define NHEADS 16
#define DHEAD 64
#define WIN 256

__device__ __forceinline__ float bf2f(u16 u) {
  union { unsigned int i; float f; } v; v.i = ((unsigned int)u) << 16; return v.f;
}
__device__ __forceinline__ u16 f2bf(float f) {
  unsigned int u = __float_as_uint(f);
  u = u + 0x7fffu + ((u >> 16) & 1u);   // RNE
  return (u16)(u >> 16);
}
__device__ __forceinline__ void async16(const void* g, void* l) {
  void* gv = const_cast<void*>(g);
  __builtin_amdgcn_global_load_lds(
      (__attribute__((address_space(1))) void*)gv,
      (__attribute__((address_space(3))) void*)l, 16, 0, 0);
}

// Inline dtype probe: 1 if x[0..255] plausible as fp32. Wave-uniform (ballot),
// deterministic across all blocks/kernels -> no separate detect kernel needed.
__device__ __forceinline__ int is_f32_probe(const void* x) {
  const float* xf = (const float*)x;
  const int lane = threadIdx.x & 63;
  int bad = 0;
  #pragma unroll
  for (int u = 0; u < 4; ++u) {
    const float v = xf[lane * 4 + u];
    const float a = fabsf(v);
    bad |= (!(a < 64.f)) || (!(v == 0.f || a > 1e-30f));
  }
  return __any(bad) ? 0 : 1;
}

// ---------------- fused prep: xconv + transpose(w_qkv) + transpose(w_out) ------------
__global__ __launch_bounds__(256) void prep(
    const void* __restrict__ x, const void* __restrict__ w_qkv,
    const void* __restrict__ w_out, u16* __restrict__ xbf,
    u16* __restrict__ wqkvT, u16* __restrict__ woutT, int have_x)
{
  const int bid = blockIdx.x;
  const int tid = threadIdx.x;
  const int isf = is_f32_probe(x);

  if (bid < 4096) {                       // ---- xconv ----
    if (!have_x) return;
    const size_t e = ((size_t)bid * 256 + tid) * 8;
    if (isf) {
      const float* f = (const float*)x;
      us4 o0, o1;
      #pragma unroll
      for (int u = 0; u < 4; ++u) { o0[u] = f2bf(f[e + u]); o1[u] = f2bf(f[e + 4 + u]); }
      *(us4*)&xbf[e] = o0; *(us4*)&xbf[e + 4] = o1;
    } else {
      *(us4*)&xbf[e]     = *(const us4*)&((const u16*)x)[e];
      *(us4*)&xbf[e + 4] = *(const us4*)&((const u16*)x)[e + 4];
    }
  } else {                                // ---- transposes ----
    __shared__ alignas(16) u16 tile[32][33];
    const void* in; u16* out; int C, bx, by;
    if (bid < 4096 + 3072) { const int t = bid - 4096; in = w_qkv; out = wqkvT; C = 3072; bx = t % 96; by = t / 96; }
    else                   { const int t = bid - 7168; in = w_out; out = woutT; C = 1024; bx = t % 32; by = t / 32; }
    const int R = 1024;
    const int tx = tid & 31, ty = tid >> 5;
    const int xg = bx * 32 + tx;
    const int y0 = by * 32;
    #pragma unroll
    for (int i = ty; i < 32; i += 8) {
      u16 v;
      if (isf) v = f2bf(((const float*)in)[(size_t)(y0 + i) * C + xg]);
      else     v = ((const u16*)in)[(size_t)(y0 + i) * C + xg];
      tile[i][tx] = v;
    }
    __syncthreads();
    const int ox  = y0 + tx;
    const int oy0 = bx * 32;
    #pragma unroll
    for (int i = ty; i < 32; i += 8)
      out[(size_t)(oy0 + i) * R + ox] = tile[tx][i];
  }
}

// ---------------- bf16 GEMM, C[M,N] = A[M,K(lda)] * Bt[N,K]^T ----------------
// BK=64; 128x128 tile. LDS row = 128B (8 chunks of 16B); slot (row,c) holds
// GLOBAL chunk c ^ (row&7) -> conflict-free b128 frag reads.
template<bool ADYN, bool CDYN>
__global__ __launch_bounds__(256, 4) void gemm_bt(
    const void* __restrict__ A, const u16* __restrict__ Bt,
    void* __restrict__ C, int N, int K, int lda, int ldc,
    const void* __restrict__ xprobe)
{
  __shared__ alignas(16) u16 As[128 * 64];
  __shared__ alignas(16) u16 Bs[128 * 64];

  const int isf  = (ADYN || CDYN) ? is_f32_probe(xprobe) : 0;
  const int tid  = threadIdx.x;
  const int lane = tid & 63;
  const int w    = tid >> 6;
  const int wm   = (w >> 1) * 64;
  const int wn   = (w & 1) * 64;
  const int quad = lane >> 4;
  const int l16  = lane & 15;
  const int row0 = blockIdx.y * 128;
  const int col0 = blockIdx.x * 128;

  f4 acc[4][4] = {};

  size_t aoff[4]; const u16* bsrc[4]; int lofs[4];
  #pragma unroll
  for (int s = 0; s < 4; ++s) {
    const int r  = s * 32 + (tid >> 3);
    const int gc = (tid & 7) ^ (r & 7);
    aoff[s] = (size_t)(row0 + r) * lda + gc * 8;
    bsrc[s] = Bt + (size_t)(col0 + r) * K + gc * 8;
    lofs[s] = s * 4096 + tid * 16;
  }

  const bool af32 = ADYN && isf;

  for (int k0 = 0; k0 < K; k0 += 64) {
    if (af32) {
      const float* Af = (const float*)A;
      bh8 a[4];
      #pragma unroll
      for (int s = 0; s < 4; ++s) {
        f4 u0 = *(const f4*)(Af + aoff[s] + k0);
        f4 u1 = *(const f4*)(Af + aoff[s] + k0 + 4);
        #pragma unroll
        for (int u = 0; u < 4; ++u) { a[s][u] = (short)f2bf(u0[u]); a[s][u + 4] = (short)f2bf(u1[u]); }
      }
      __syncthreads();
      #pragma unroll
      for (int s = 0; s < 4; ++s) {
        *(bh8*)((char*)As + lofs[s]) = a[s];
        async16(bsrc[s] + k0, (char*)Bs + lofs[s]);
      }
    } else {
      const u16* A16 = (const u16*)A;
      __syncthreads();
      #pragma unroll
      for (int s = 0; s < 4; ++s) {
        async16(A16 + aoff[s] + k0, (char*)As + lofs[s]);
        async16(bsrc[s] + k0,       (char*)Bs + lofs[s]);
      }
    }
    __builtin_amdgcn_s_waitcnt(0);
    __syncthreads();

    #pragma unroll
    for (int ks = 0; ks < 2; ++ks) {
      bh8 af[4], bf[4];
      #pragma unroll
      for (int i = 0; i < 4; ++i) {
        const int row = wm + i * 16 + l16;
        const int lc  = (ks * 4 + quad) ^ (row & 7);
        af[i] = *(const bh8*)(As + row * 64 + lc * 8);
      }
      #pragma unroll
      for (int j = 0; j < 4; ++j) {
        const int row = wn + j * 16 + l16;
        const int lc  = (ks * 4 + quad) ^ (row & 7);
        bf[j] = *(const bh8*)(Bs + row * 64 + lc * 8);
      }
      #pragma unroll
      for (int i = 0; i < 4; ++i)
        #pragma unroll
        for (int j = 0; j < 4; ++j)
          acc[i][j] = __builtin_amdgcn_mfma_f32_16x16x32_bf16(af[i], bf[j], acc[i][j], 0, 0, 0);
    }
  }

  const bool cf32 = CDYN && isf;
  #pragma unroll
  for (int i = 0; i < 4; ++i) {
    #pragma unroll
    for (int j = 0; j < 4; ++j) {
      const int rb = row0 + wm + i * 16 + quad * 4;
      const int cc = col0 + wn + j * 16 + l16;
      #pragma unroll
      for (int r = 0; r < 4; ++r) {
        if (cf32) ((float*)C)[(size_t)(rb + r) * ldc + cc] = acc[i][j][r];
        else      ((u16*)C)[(size_t)(rb + r) * ldc + cc]   = f2bf(acc[i][j][r]);
      }
    }
  }
}

// ---------------- MFMA flash-style sliding-window attention ----------------
// Q frags in registers (pre-scaled by 1/sqrt(d)); LDS = Kt+Vt+Ps = 27.6 KB.
// Mask algebra: with 64-row tiles and WIN=256, tiles t=1..3 are fully inside
// the window (no mask); t=4 (diagonal) needs only j<=i and t=0 (left edge,
// qb>=4) only j>i-WIN, and both reduce to the single kb==w sub-tile; sub-tiles
// strictly past the diagonal are fully dead -> their QK MFMAs are skipped.
__global__ __launch_bounds__(256) void attn_mfma(const u16* __restrict__ qkv,
                                                 u16* __restrict__ att, int ldo)
{
  __shared__ alignas(16) u16 Kt[64 * 72];
  __shared__ alignas(16) u16 Vt[64 * 72];   // (d,k): d*72 + ((k>>3)^(d>>3))*8 + (k&7)
  __shared__ alignas(16) u16 Ps[64 * 72];   // (q,k): q*72 + ((k>>3)^((q>>3)&1))*8 + (k&7)

  const int tid  = threadIdx.x;
  const int lane = tid & 63;
  const int w    = tid >> 6;
  const int quad = lane >> 4;
  const int l16  = lane & 15;
  const int qb = blockIdx.x, h = blockIdx.y, b = blockIdx.z;
  const int qs = qb * 64;

  const u16* base = qkv + (size_t)b * T_SEQ * 3072 + h * 64;

  // Q frags, pre-scaled by 0.125 (folds the softmax 1/sqrt(64) once per block)
  const size_t qrowg = (size_t)(qs + w * 16 + l16) * 3072;
  bh8 qa0 = *(const bh8*)&base[qrowg + quad * 8];
  bh8 qa1 = *(const bh8*)&base[qrowg + 32 + quad * 8];
  #pragma unroll
  for (int u = 0; u < 8; ++u) {
    qa0[u] = (short)f2bf(bf2f((u16)qa0[u]) * 0.125f);
    qa1[u] = (short)f2bf(bf2f((u16)qa1[u]) * 0.125f);
  }

  f4 Oc[4] = {};
  float mst[4] = {-1e30f, -1e30f, -1e30f, -1e30f};
  float lst[4] = {0.f, 0.f, 0.f, 0.f};

  const int tmin = (qb >= 4) ? 0 : (4 - qb);
  const int c8  = (tid & 7) * 8;
  const int r0s = tid >> 3;

  for (int t = tmin; t < 5; ++t) {
    const int kt0 = qs - 256 + t * 64;
    const bool diag  = (t == 4);          // only j<=i can fail
    const bool ledge = (t == 0);          // only reached when qb>=4; only j>i-WIN can fail
    const int kb_lo = ledge ? w : 0;      // kb<w fully masked on left edge
    const int kb_hi = diag  ? w : 3;      // kb>w fully masked on diagonal
    __syncthreads();

    #pragma unroll
    for (int r = r0s; r < 64; r += 32) {
      *(bh8*)&Kt[r * 72 + c8] =
          *(const bh8*)&base[(size_t)(kt0 + r) * 3072 + 1024 + c8];
      bh8 v = *(const bh8*)&base[(size_t)(kt0 + r) * 3072 + 2048 + c8];
      const int kc = r >> 3, ki = r & 7;
      #pragma unroll
      for (int u = 0; u < 8; ++u) {
        const int d = c8 + u;
        Vt[d * 72 + ((kc ^ (d >> 3)) << 3) + ki] = (u16)v[u];
      }
    }
    __syncthreads();

    f4 S[4];
    #pragma unroll
    for (int kb = 0; kb < 4; ++kb) {
      if (kb < kb_lo || kb > kb_hi) {
        S[kb][0] = S[kb][1] = S[kb][2] = S[kb][3] = -1e30f;
      } else {
        const int krow = (kb * 16 + l16) * 72;
        bh8 kf0 = *(const bh8*)&Kt[krow + quad * 8];
        bh8 kf1 = *(const bh8*)&Kt[krow + 32 + quad * 8];
        f4 s = {};
        s = __builtin_amdgcn_mfma_f32_16x16x32_bf16(qa0, kf0, s, 0, 0, 0);
        s = __builtin_amdgcn_mfma_f32_16x16x32_bf16(qa1, kf1, s, 0, 0, 0);
        S[kb] = s;
      }
    }

    // mask: only the kb==w sub-tile of a masked tile has mixed elements
    if (diag || ledge) {
      #pragma unroll
      for (int kb = 0; kb < 4; ++kb) {
        if (kb == w) {
          #pragma unroll
          for (int rr = 0; rr < 4; ++rr) {
            const int ii = quad * 4 + rr;
            const bool ok = diag ? (l16 <= ii) : (l16 > ii);
            if (!ok) S[kb][rr] = -1e30f;
          }
        }
      }
    }

    float tmax[4] = {-1e30f, -1e30f, -1e30f, -1e30f};
    #pragma unroll
    for (int kb = 0; kb < 4; ++kb)
      #pragma unroll
      for (int rr = 0; rr < 4; ++rr)
        tmax[rr] = fmaxf(tmax[rr], S[kb][rr]);
    #pragma unroll
    for (int off = 1; off < 16; off <<= 1)
      #pragma unroll
      for (int rr = 0; rr < 4; ++rr)
        tmax[rr] = fmaxf(tmax[rr], __shfl_xor(tmax[rr], off));

    // defer-max (T13): skip rescale while the running max grows < 8
    const bool grew = (tmax[0] > mst[0] + 8.f) || (tmax[1] > mst[1] + 8.f) ||
                      (tmax[2] > mst[2] + 8.f) || (tmax[3] > mst[3] + 8.f);
    if (__any(grew)) {
      #pragma unroll
      for (int rr = 0; rr < 4; ++rr) {
        const float mnew = fmaxf(mst[rr], tmax[rr]);
        const float al = __expf(mst[rr] - mnew);
        mst[rr] = mnew;
        lst[rr] *= al;
        #pragma unroll
        for (int db = 0; db < 4; ++db) Oc[db][rr] *= al;
      }
    }

    float rsum[4] = {0.f, 0.f, 0.f, 0.f};
    const int swq = quad >> 1;
    #pragma unroll
    for (int kb = 0; kb < 4; ++kb) {
      const int kc = kb * 2 + (l16 >> 3);
      const int ki = l16 & 7;
      #pragma unroll
      for (int rr = 0; rr < 4; ++rr) {
        const float p = __expf(S[kb][rr] - mst[rr]);  // masked: exp(-1e30)->0
        rsum[rr] += p;
        const int q = w * 16 + quad * 4 + rr;
        Ps[q * 72 + ((kc ^ swq) << 3) + ki] = f2bf(p);
      }
    }
    #pragma unroll
    for (int off = 1; off < 16; off <<= 1)
      #pragma unroll
      for (int rr = 0; rr < 4; ++rr)
        rsum[rr] += __shfl_xor(rsum[rr], off);
    #pragma unroll
    for (int rr = 0; rr < 4; ++rr)
      lst[rr] += rsum[rr];

    {
      const int q = w * 16 + l16;
      const int sw = (q >> 3) & 1;
      bh8 pa0 = *(const bh8*)&Ps[q * 72 + (((0 + quad) ^ sw) << 3)];
      bh8 pa1 = *(const bh8*)&Ps[q * 72 + (((4 + quad) ^ sw) << 3)];
      #pragma unroll
      for (int db = 0; db < 4; ++db) {
        const int d = db * 16 + l16;
        const int dsw = d >> 3;
        bh8 vb0 = *(const bh8*)&Vt[d * 72 + (((0 + quad) ^ dsw) << 3)];
        bh8 vb1 = *(const bh8*)&Vt[d * 72 + (((4 + quad) ^ dsw) << 3)];
        Oc[db] = __builtin_amdgcn_mfma_f32_16x16x32_bf16(pa0, vb0, Oc[db], 0, 0, 0);
        Oc[db] = __builtin_amdgcn_mfma_f32_16x16x32_bf16(pa1, vb1, Oc[db], 0, 0, 0);
      }
    }
  }

  u16* obase = att + (size_t)b * T_SEQ * ldo + h * 64;
  #pragma unroll
  for (int rr = 0; rr < 4; ++rr) {
    const int i = qs + w * 16 + quad * 4 + rr;
    const float inv = 1.f / lst[rr];
    #pragma unroll
    for (int db = 0; db < 4; ++db)
      obase[(size_t)i * ldo + db * 16 + l16] = f2bf(Oc[db][rr] * inv);
  }
}

// ---------------- launcher ----------------
extern "C" void kernel_launch(void* const* d_in, const int* in_sizes, int n_in,
                              void* d_out, int out_size, void* d_ws, size_t ws_size,
                              hipStream_t stream) {
  const void* x     = d_in[0];   // [8192, 1024]  fp32 or bf16 (auto-detected)
  const void* w_qkv = d_in[1];   // [1024, 3072]
  const void* w_out = d_in[2];   // [1024, 1024]

  const size_t SZ_QKV = (size_t)8192 * 3072 * 2;
  const size_t SZ_XBF = (size_t)8192 * 1024 * 2;
  const size_t SZ_WQ  = (size_t)3072 * 1024 * 2;
  const size_t SZ_WO  = (size_t)1024 * 1024 * 2;
  const size_t SZ_ATT = (size_t)8192 * 1024 * 2;

  char* p = (char*)d_ws;
  u16* qkv   = (u16*)p; p += SZ_QKV;
  u16* wqkvT = (u16*)p; p += SZ_WQ;
  u16* woutT = (u16*)p; p += SZ_WO;
  u16* xbf   = (u16*)p; p += SZ_XBF;
  u16* attb  = (u16*)p;
  const size_t need_x   = SZ_QKV + SZ_WQ + SZ_WO + SZ_XBF;
  const bool have_x   = ws_size >= need_x;
  const bool have_att = ws_size >= need_x + SZ_ATT;

  prep<<<dim3(8192), 256, 0, stream>>>(x, w_qkv, w_out, xbf, wqkvT, woutT,
                                       have_x ? 1 : 0);

  if (have_x) {
    gemm_bt<false, false><<<dim3(24, 64), 256, 0, stream>>>(
        xbf, wqkvT, qkv, 3072, 1024, 1024, 3072, x);
  } else {
    gemm_bt<true, false><<<dim3(24, 64), 256, 0, stream>>>(
        x, wqkvT, qkv, 3072, 1024, 1024, 3072, x);
  }

  // attention: compact output when ws allows, else in-place q-channel
  u16* attp  = have_att ? attb : qkv;
  const int ldo = have_att ? 1024 : 3072;
  attn_mfma<<<dim3(32, NHEADS, 4), 256, 0, stream>>>(qkv, attp, ldo);

  gemm_bt<false, true><<<dim3(8, 64), 256, 0, stream>>>(
      attp, woutT, d_out, 1024, 1024, ldo, 1024, x);
}